// Round 1
// baseline (1022.966 us; speedup 1.0000x reference)
//
#include <hip/hip_runtime.h>

#define BATCH 4
#define DIM   1536
#define SEQ   4096
#define NST   16
#define NCHAN (BATCH*DIM)

#define T     8          // timesteps staged per subtile
#define LSTR  9          // padded LDS row stride (floats): 64 lanes * stride 9 -> 2-way (free)
#define WLDS  (64*LSTR)  // per-wave u/dt slice (floats)

#define LOG2E 1.4426950408889634f

// softplus matching jax.nn.softplus = log1p(exp(z)), overflow-safe
__device__ __forceinline__ float softplus_f(float z) {
    return (z > 20.f) ? z : __logf(1.f + __expf(z));
}
__device__ __forceinline__ float exp2_hw(float z) {
    return __builtin_amdgcn_exp2f(z);
}

// ---------------- Phase A: per-(channel,chunk) summaries ----------------
// S_n = sum_t (prod_{t'>t} a_{t'}) b_t dtu_t   (local recurrence, x_in = 0)
// sumdt = sum_t dt_t   (chunk decay = exp2(A2_n*sumdt))
// Wave-private LDS staging, in-wave pipelined global loads, NO barriers.
// Staging geometry (T=8): lane covers rows {ro, 32+ro}, cols c4..c4+3.
// softplus is applied AT STAGING (per staged-row bias), so the inner loop
// reads ready-made dt from LDS.
template<int CLEN>
__global__ __launch_bounds__(256, 6) void ssm_phaseA(
    const float* __restrict__ u, const float* __restrict__ delta,
    const float* __restrict__ Bm, const float* __restrict__ A,
    const float* __restrict__ dbias,
    float* __restrict__ sumdt_out, float* __restrict__ S_out)
{
    __shared__ float lu[4 * WLDS];
    __shared__ float ld[4 * WLDS];
    __shared__ float lB[4 * T * NST];

    const int tid = threadIdx.x;
    const int w   = tid >> 6;
    const int l   = tid & 63;
    const int ch  = blockIdx.x * 256 + tid;
    const int d   = ch % DIM;
    const int bb  = (blockIdx.x * 256) / DIM;   // uniform per block (1536 % 256 == 0)
    const int k   = blockIdx.y;
    const int s0  = k * CLEN;

    float* Lu = &lu[w * WLDS];
    float* Ld = &ld[w * WLDS];
    float* LB = &lB[w * T * NST];

    float A2[NST];
    const float* Ap = A + d * NST;
#pragma unroll
    for (int n = 0; n < NST; n++) A2[n] = Ap[n] * LOG2E;

    // staging geometry
    const int ro = l >> 1;           // 0..31
    const int c4 = (l & 1) << 2;     // 0 or 4
    const int dS = (blockIdx.x * 256 + w * 64) % DIM;  // d of this wave's row 0
    const float sb0 = dbias[dS + ro];
    const float sb1 = dbias[dS + 32 + ro];

    const size_t rowbase = (size_t)(blockIdx.x * 256 + w * 64) * SEQ + s0;
    const int nb = ro & 15;          // B row for lanes < 32
    const size_t bbase = (size_t)(bb * NST + nb) * SEQ + s0;

    float4 ru[2], rd[2], rb;
#pragma unroll
    for (int q = 0; q < 2; q++) {
        const size_t g = rowbase + (size_t)(q * 32 + ro) * SEQ + c4;
        ru[q] = *(const float4*)(u + g);
        rd[q] = *(const float4*)(delta + g);
    }
    if (l < 32) rb = *(const float4*)(Bm + bbase + c4);

    float S[NST];
#pragma unroll
    for (int n = 0; n < NST; n++) S[n] = 0.f;
    float sumdt = 0.f;

    for (int ss = 0; ss < CLEN; ss += T) {
        // dump tile regs -> wave-private LDS (in-order DS pipe, no barrier)
#pragma unroll
        for (int q = 0; q < 2; q++) {
            const float sb = q ? sb1 : sb0;
            float* pu = &Lu[(q * 32 + ro) * LSTR + c4];
            float* pd = &Ld[(q * 32 + ro) * LSTR + c4];
            pu[0] = ru[q].x; pu[1] = ru[q].y; pu[2] = ru[q].z; pu[3] = ru[q].w;
            pd[0] = softplus_f(rd[q].x + sb);
            pd[1] = softplus_f(rd[q].y + sb);
            pd[2] = softplus_f(rd[q].z + sb);
            pd[3] = softplus_f(rd[q].w + sb);
        }
        if (l < 32) {
            LB[(c4 + 0) * NST + nb] = rb.x;
            LB[(c4 + 1) * NST + nb] = rb.y;
            LB[(c4 + 2) * NST + nb] = rb.z;
            LB[(c4 + 3) * NST + nb] = rb.w;
        }

        // prefetch next tile while computing this one
        if (ss + T < CLEN) {
#pragma unroll
            for (int q = 0; q < 2; q++) {
                const size_t g = rowbase + (size_t)(q * 32 + ro) * SEQ + (ss + T) + c4;
                ru[q] = *(const float4*)(u + g);
                rd[q] = *(const float4*)(delta + g);
            }
            if (l < 32) rb = *(const float4*)(Bm + bbase + (ss + T) + c4);
        }

        const float* lur = &Lu[l * LSTR];
        const float* ldr = &Ld[l * LSTR];
#pragma unroll
        for (int i = 0; i < T; i++) {
            const float uu  = lur[i];
            const float dt  = ldr[i];
            const float dtu = dt * uu;
            sumdt += dt;
            const float* bi = &LB[i * NST];
#pragma unroll
            for (int n = 0; n < NST; n++) {
                const float a = exp2_hw(dt * A2[n]);
                S[n] = fmaf(a, S[n], dtu * bi[n]);
            }
        }
    }

    const size_t base = ((size_t)k * NCHAN + ch) * NST;   // [k][ch][n]
#pragma unroll
    for (int n = 0; n < NST; n += 4)
        *(float4*)(S_out + base + n) = make_float4(S[n], S[n+1], S[n+2], S[n+3]);
    sumdt_out[(size_t)k * NCHAN + ch] = sumdt;
}

// ---------------- Phase B: scan chunk summaries -> chunk entry states ----
// In-place on S[k][ch][n]: becomes x0 (state entering chunk k).
// Software-pipelined: next chunk's loads are issued BEFORE the in-place
// store, so the (conservative) aliasing between S-load and S-store never
// serializes the loop.
template<int NCH>
__global__ __launch_bounds__(256) void ssm_phaseB(
    const float* __restrict__ A, const float* __restrict__ sumdt,
    float* __restrict__ S)
{
    const int t  = blockIdx.x * 256 + threadIdx.x;
    const int n  = t & 15;
    const int ch = t >> 4;
    if (ch >= NCHAN) return;
    const int d = ch % DIM;
    const float An2 = A[d * NST + n] * LOG2E;

    const size_t kstride = (size_t)NCHAN * NST;
    size_t idx = (size_t)ch * NST + n;

    float x = 0.f;
    float s_nxt = S[idx];
    float p_nxt = sumdt[ch];
#pragma unroll 4
    for (int k = 0; k < NCH; k++) {
        const float s_old = s_nxt;
        const float pdt   = p_nxt;
        if (k + 1 < NCH) {
            s_nxt = S[idx + kstride];
            p_nxt = sumdt[(size_t)(k + 1) * NCHAN + ch];
        }
        S[idx] = x;                                   // x0 for chunk k
        x = fmaf(exp2_hw(An2 * pdt), x, s_old);       // state after chunk k
        idx += kstride;
    }
}

// ---------------- Phase C: replay chunk from x0, emit y ------------------
// Same wave-private pipelined structure; y reuses the u LDS slice.
// Lanes < 32 stage B, lanes >= 32 stage C (shared rbc register).
template<int CLEN>
__global__ __launch_bounds__(256, 6) void ssm_phaseC(
    const float* __restrict__ u, const float* __restrict__ delta,
    const float* __restrict__ Bm, const float* __restrict__ Cm,
    const float* __restrict__ A, const float* __restrict__ Dv,
    const float* __restrict__ dbias, const float* __restrict__ x0,
    float* __restrict__ y)
{
    __shared__ float lu[4 * WLDS];
    __shared__ float ld[4 * WLDS];
    __shared__ float lB[4 * T * NST];
    __shared__ float lC[4 * T * NST];

    const int tid = threadIdx.x;
    const int w   = tid >> 6;
    const int l   = tid & 63;
    const int ch  = blockIdx.x * 256 + tid;
    const int d   = ch % DIM;
    const int bb  = (blockIdx.x * 256) / DIM;
    const int k   = blockIdx.y;
    const int s0  = k * CLEN;

    float* Lu = &lu[w * WLDS];
    float* Ld = &ld[w * WLDS];
    float* LB = &lB[w * T * NST];
    float* LC = &lC[w * T * NST];

    float A2[NST];
    const float* Ap = A + d * NST;
#pragma unroll
    for (int n = 0; n < NST; n++) A2[n] = Ap[n] * LOG2E;
    const float Dval = Dv[d];

    float x[NST];
    const size_t xbase = ((size_t)k * NCHAN + ch) * NST;
#pragma unroll
    for (int n = 0; n < NST; n += 4) {
        const float4 xv = *(const float4*)(x0 + xbase + n);
        x[n] = xv.x; x[n+1] = xv.y; x[n+2] = xv.z; x[n+3] = xv.w;
    }

    const int ro = l >> 1;
    const int c4 = (l & 1) << 2;
    const int dS = (blockIdx.x * 256 + w * 64) % DIM;
    const float sb0 = dbias[dS + ro];
    const float sb1 = dbias[dS + 32 + ro];

    const size_t rowbase = (size_t)(blockIdx.x * 256 + w * 64) * SEQ + s0;
    const int nb = ro & 15;                  // lanes<32: B row; lanes>=32: C row
    const float* BC = (l < 32) ? Bm : Cm;
    const size_t bbase = (size_t)(bb * NST + nb) * SEQ + s0;

    float4 ru[2], rd[2], rbc;
#pragma unroll
    for (int q = 0; q < 2; q++) {
        const size_t g = rowbase + (size_t)(q * 32 + ro) * SEQ + c4;
        ru[q] = *(const float4*)(u + g);
        rd[q] = *(const float4*)(delta + g);
    }
    rbc = *(const float4*)(BC + bbase + c4);

    for (int ss = 0; ss < CLEN; ss += T) {
#pragma unroll
        for (int q = 0; q < 2; q++) {
            const float sb = q ? sb1 : sb0;
            float* pu = &Lu[(q * 32 + ro) * LSTR + c4];
            float* pd = &Ld[(q * 32 + ro) * LSTR + c4];
            pu[0] = ru[q].x; pu[1] = ru[q].y; pu[2] = ru[q].z; pu[3] = ru[q].w;
            pd[0] = softplus_f(rd[q].x + sb);
            pd[1] = softplus_f(rd[q].y + sb);
            pd[2] = softplus_f(rd[q].z + sb);
            pd[3] = softplus_f(rd[q].w + sb);
        }
        {
            float* dst = (l < 32) ? LB : LC;
            dst[(c4 + 0) * NST + nb] = rbc.x;
            dst[(c4 + 1) * NST + nb] = rbc.y;
            dst[(c4 + 2) * NST + nb] = rbc.z;
            dst[(c4 + 3) * NST + nb] = rbc.w;
        }

        if (ss + T < CLEN) {
#pragma unroll
            for (int q = 0; q < 2; q++) {
                const size_t g = rowbase + (size_t)(q * 32 + ro) * SEQ + (ss + T) + c4;
                ru[q] = *(const float4*)(u + g);
                rd[q] = *(const float4*)(delta + g);
            }
            rbc = *(const float4*)(BC + bbase + (ss + T) + c4);
        }

        float* lur = &Lu[l * LSTR];
        const float* ldr = &Ld[l * LSTR];
#pragma unroll
        for (int i = 0; i < T; i++) {
            const float uu  = lur[i];
            const float dt  = ldr[i];
            const float dtu = dt * uu;
            const float* bi = &LB[i * NST];
            const float* ci = &LC[i * NST];
            float acc = Dval * uu;
#pragma unroll
            for (int n = 0; n < NST; n++) {
                const float a = exp2_hw(dt * A2[n]);
                x[n] = fmaf(a, x[n], dtu * bi[n]);
                acc  = fmaf(x[n], ci[n], acc);
            }
            lur[i] = acc;   // overwrite u slot with y (same-lane read-then-write)
        }

        // coalesced y writeout (transposed read of the wave's slice)
#pragma unroll
        for (int q = 0; q < 2; q++) {
            const float* pr = &Lu[(q * 32 + ro) * LSTR + c4];
            *(float4*)(y + rowbase + (size_t)(q * 32 + ro) * SEQ + ss + c4) =
                make_float4(pr[0], pr[1], pr[2], pr[3]);
        }
    }
}

template<int CLEN>
static void run_pipeline(const float* u, const float* delta, const float* Bm,
                         const float* Cm, const float* A, const float* Dv,
                         const float* dbias, float* y, float* ws,
                         hipStream_t stream)
{
    constexpr int NCH = SEQ / CLEN;
    float* sumdt = ws;
    float* S     = ws + (size_t)NCH * NCHAN;

    const dim3 grid(NCHAN / 256, NCH);
    ssm_phaseA<CLEN><<<grid, 256, 0, stream>>>(u, delta, Bm, A, dbias, sumdt, S);
    ssm_phaseB<NCH><<<(NCHAN * NST) / 256, 256, 0, stream>>>(A, sumdt, S);
    ssm_phaseC<CLEN><<<grid, 256, 0, stream>>>(u, delta, Bm, Cm, A, Dv, dbias, S, y);
}

extern "C" void kernel_launch(void* const* d_in, const int* in_sizes, int n_in,
                              void* d_out, int out_size, void* d_ws, size_t ws_size,
                              hipStream_t stream)
{
    const float* u     = (const float*)d_in[0];
    const float* delta = (const float*)d_in[1];
    const float* Bm    = (const float*)d_in[2];
    const float* Cm    = (const float*)d_in[3];
    const float* A     = (const float*)d_in[4];
    const float* Dv    = (const float*)d_in[5];
    const float* dbias = (const float*)d_in[6];
    float* y  = (float*)d_out;
    float* ws = (float*)d_ws;

    // primary: 64 chunks of 64 -> ws = sumdt (64*NCHAN) + S (64*NCHAN*NST) ~ 26.7 MB
    const size_t need64 = ((size_t)64 * NCHAN + (size_t)64 * NCHAN * NST) * sizeof(float);
    if (ws_size >= need64) {
        run_pipeline<64>(u, delta, Bm, Cm, A, Dv, dbias, y, ws, stream);
    } else {
        // fallback: 32 chunks of 128 (~13.4 MB), same math
        run_pipeline<128>(u, delta, Bm, Cm, A, Dv, dbias, y, ws, stream);
    }
}

// Round 2
// 537.620 us; speedup vs baseline: 1.9028x; 1.9028x over previous
//
#include <hip/hip_runtime.h>

#define BATCH 4
#define DIM   1536
#define SEQ   4096
#define NST   16
#define NCHAN (BATCH*DIM)
#define NCH   32       // chunks per sequence
#define CLEN  128      // chunk length: NCH*CLEN == SEQ
#define T     16       // timesteps per staged subtile (64B per row per access)
#define LBSTR 20       // LDS B/C tile stride ([t][n], padded: write conflicts <=2-way)

#define LOG2E 1.4426950408889634f

// softplus matching jax.nn.softplus = log1p(exp(z)), overflow-safe
__device__ __forceinline__ float softplus_f(float z) {
    return (z > 20.f) ? z : __logf(1.f + __expf(z));
}
__device__ __forceinline__ float exp2_hw(float z) {
    return __builtin_amdgcn_exp2f(z);
}

// DPP quad_perm helper (compile-time control). All lanes active, uniform flow.
template<int CTRL>
__device__ __forceinline__ float dpp_qp(float v) {
    return __int_as_float(
        __builtin_amdgcn_mov_dpp(__float_as_int(v), CTRL, 0xf, 0xf, true));
}
// sum across the 4 lanes of a quad (result in all 4 lanes)
__device__ __forceinline__ float quad_sum(float v) {
    v += dpp_qp<0xB1>(v);   // quad_perm [1,0,3,2]
    v += dpp_qp<0x4E>(v);   // quad_perm [2,3,0,1]
    return v;
}

// ---------------------------------------------------------------------------
// Decomposition: each CHANNEL is owned by a 4-lane quad; lane sub owns states
// n = sub*4..sub*4+3. Lane's own float4 global load covers 4 timesteps of its
// own channel row -> no LDS transpose for u/dt; timestep values are shared
// within the quad via DPP quad_perm broadcasts. Only B/C tiles go to LDS
// ([t][n] layout, broadcast b128 reads). Wave = 16 channels. Block = 4 waves
// = 64 channels. Grid = (NCHAN/64, NCH) = (96, 32) = 3072 blocks -> up to
// 32 waves/CU (HW cap) vs 12 before.
// ---------------------------------------------------------------------------

// ---------------- Phase A: per-(channel,chunk) summaries ----------------
__global__ __launch_bounds__(256, 6) void ssm_phaseA(
    const float* __restrict__ u, const float* __restrict__ delta,
    const float* __restrict__ Bm, const float* __restrict__ A,
    const float* __restrict__ dbias,
    float* __restrict__ sumdt_out, float* __restrict__ S_out)
{
    __shared__ float lB[4 * T * LBSTR];

    const int tid = threadIdx.x;
    const int w   = tid >> 6;
    const int l   = tid & 63;
    const int q   = l >> 2;      // quad index = channel row in wave = B state row
    const int sub = l & 3;       // lane within quad: owns states sub*4..+3
    const int cj  = sub << 2;    // this lane's 4-timestep column slot in a tile

    const int ch0 = blockIdx.x * 64;
    const int ch  = ch0 + w * 16 + q;
    const int d   = ch % DIM;
    const int bb  = ch0 / DIM;   // batch (64 | 1536, no straddle)
    const int k   = blockIdx.y;
    const int s0  = k * CLEN;

    float* LB = &lB[w * T * LBSTR];

    float A2[4];
    {
        const float4 av = *(const float4*)(A + (size_t)d * NST + sub * 4);
        A2[0] = av.x * LOG2E; A2[1] = av.y * LOG2E;
        A2[2] = av.z * LOG2E; A2[3] = av.w * LOG2E;
    }
    const float sbias = dbias[d];

    const size_t ubase = (size_t)ch * SEQ + s0;
    const size_t bbase = ((size_t)bb * NST + q) * SEQ + s0;

    float4 run = *(const float4*)(u + ubase + cj);
    float4 rdn = *(const float4*)(delta + ubase + cj);
    float4 rbn = *(const float4*)(Bm + bbase + cj);

    float S[4] = {0.f, 0.f, 0.f, 0.f};
    float sumdt = 0.f;

    for (int ss = 0; ss < CLEN; ss += T) {
        // unpack current tile into register arrays (static indexing only)
        const float uc[4] = {run.x, run.y, run.z, run.w};
        const float dc[4] = {softplus_f(rdn.x + sbias), softplus_f(rdn.y + sbias),
                             softplus_f(rdn.z + sbias), softplus_f(rdn.w + sbias)};
        sumdt += (dc[0] + dc[1]) + (dc[2] + dc[3]);

        // stage B tile [t][n] (4 scatter writes, <=2-way bank alias with LBSTR=20)
        LB[(cj + 0) * LBSTR + q] = rbn.x;
        LB[(cj + 1) * LBSTR + q] = rbn.y;
        LB[(cj + 2) * LBSTR + q] = rbn.z;
        LB[(cj + 3) * LBSTR + q] = rbn.w;

        // prefetch next tile (64B per row, sector-aligned)
        if (ss + T < CLEN) {
            run = *(const float4*)(u + ubase + (ss + T) + cj);
            rdn = *(const float4*)(delta + ubase + (ss + T) + cj);
            rbn = *(const float4*)(Bm + bbase + (ss + T) + cj);
        }

#define ASTEP(ii) { \
        const float dt  = dpp_qp<(((ii) >> 2) * 0x55)>(dc[(ii) & 3]); \
        const float uu  = dpp_qp<(((ii) >> 2) * 0x55)>(uc[(ii) & 3]); \
        const float dtu = dt * uu; \
        const float4 bv = *(const float4*)(&LB[(ii) * LBSTR + cj]); \
        S[0] = fmaf(exp2_hw(dt * A2[0]), S[0], dtu * bv.x); \
        S[1] = fmaf(exp2_hw(dt * A2[1]), S[1], dtu * bv.y); \
        S[2] = fmaf(exp2_hw(dt * A2[2]), S[2], dtu * bv.z); \
        S[3] = fmaf(exp2_hw(dt * A2[3]), S[3], dtu * bv.w); \
    }
        ASTEP(0)  ASTEP(1)  ASTEP(2)  ASTEP(3)
        ASTEP(4)  ASTEP(5)  ASTEP(6)  ASTEP(7)
        ASTEP(8)  ASTEP(9)  ASTEP(10) ASTEP(11)
        ASTEP(12) ASTEP(13) ASTEP(14) ASTEP(15)
#undef ASTEP
    }

    // S: lane writes its 4 states; quad writes 64B contiguous
    *(float4*)(S_out + ((size_t)k * NCHAN + ch) * NST + sub * 4) =
        make_float4(S[0], S[1], S[2], S[3]);

    const float sfull = quad_sum(sumdt);
    if (sub == 0) sumdt_out[(size_t)k * NCHAN + ch] = sfull;
}

// ---------------- Phase B: scan chunk summaries -> chunk entry states ----
// In-place on S[k][ch][n]: becomes x0 (state entering chunk k). Pipelined.
__global__ __launch_bounds__(256) void ssm_phaseB(
    const float* __restrict__ A, const float* __restrict__ sumdt,
    float* __restrict__ S)
{
    const int t  = blockIdx.x * 256 + threadIdx.x;
    const int n  = t & 15;
    const int ch = t >> 4;
    if (ch >= NCHAN) return;
    const int d = ch % DIM;
    const float An2 = A[(size_t)d * NST + n] * LOG2E;

    const size_t kstride = (size_t)NCHAN * NST;
    size_t idx = (size_t)ch * NST + n;

    float x = 0.f;
    float s_nxt = S[idx];
    float p_nxt = sumdt[ch];
#pragma unroll 4
    for (int k = 0; k < NCH; k++) {
        const float s_old = s_nxt;
        const float pdt   = p_nxt;
        if (k + 1 < NCH) {
            s_nxt = S[idx + kstride];
            p_nxt = sumdt[(size_t)(k + 1) * NCHAN + ch];
        }
        S[idx] = x;                                   // x0 for chunk k
        x = fmaf(exp2_hw(An2 * pdt), x, s_old);       // state after chunk k
        idx += kstride;
    }
}

// ---------------- Phase C: replay chunk from x0, emit y ------------------
__global__ __launch_bounds__(256, 6) void ssm_phaseC(
    const float* __restrict__ u, const float* __restrict__ delta,
    const float* __restrict__ Bm, const float* __restrict__ Cm,
    const float* __restrict__ A, const float* __restrict__ Dv,
    const float* __restrict__ dbias, const float* __restrict__ x0,
    float* __restrict__ y)
{
    __shared__ float lB[4 * T * LBSTR];
    __shared__ float lC[4 * T * LBSTR];

    const int tid = threadIdx.x;
    const int w   = tid >> 6;
    const int l   = tid & 63;
    const int q   = l >> 2;
    const int sub = l & 3;
    const int cj  = sub << 2;

    const int ch0 = blockIdx.x * 64;
    const int ch  = ch0 + w * 16 + q;
    const int d   = ch % DIM;
    const int bb  = ch0 / DIM;
    const int k   = blockIdx.y;
    const int s0  = k * CLEN;

    float* LB = &lB[w * T * LBSTR];
    float* LC = &lC[w * T * LBSTR];

    float A2[4];
    {
        const float4 av = *(const float4*)(A + (size_t)d * NST + sub * 4);
        A2[0] = av.x * LOG2E; A2[1] = av.y * LOG2E;
        A2[2] = av.z * LOG2E; A2[3] = av.w * LOG2E;
    }
    const float sbias = dbias[d];
    const float Dval  = Dv[d];

    float x[4];
    {
        const float4 xv = *(const float4*)(x0 + ((size_t)k * NCHAN + ch) * NST + sub * 4);
        x[0] = xv.x; x[1] = xv.y; x[2] = xv.z; x[3] = xv.w;
    }

    const size_t ubase = (size_t)ch * SEQ + s0;
    const size_t bbase = ((size_t)bb * NST + q) * SEQ + s0;

    float4 run = *(const float4*)(u + ubase + cj);
    float4 rdn = *(const float4*)(delta + ubase + cj);
    float4 rbn = *(const float4*)(Bm + bbase + cj);
    float4 rcn = *(const float4*)(Cm + bbase + cj);

    for (int ss = 0; ss < CLEN; ss += T) {
        const float uc[4] = {run.x, run.y, run.z, run.w};
        const float dc[4] = {softplus_f(rdn.x + sbias), softplus_f(rdn.y + sbias),
                             softplus_f(rdn.z + sbias), softplus_f(rdn.w + sbias)};

        LB[(cj + 0) * LBSTR + q] = rbn.x;
        LB[(cj + 1) * LBSTR + q] = rbn.y;
        LB[(cj + 2) * LBSTR + q] = rbn.z;
        LB[(cj + 3) * LBSTR + q] = rbn.w;
        LC[(cj + 0) * LBSTR + q] = rcn.x;
        LC[(cj + 1) * LBSTR + q] = rcn.y;
        LC[(cj + 2) * LBSTR + q] = rcn.z;
        LC[(cj + 3) * LBSTR + q] = rcn.w;

        if (ss + T < CLEN) {
            run = *(const float4*)(u + ubase + (ss + T) + cj);
            rdn = *(const float4*)(delta + ubase + (ss + T) + cj);
            rbn = *(const float4*)(Bm + bbase + (ss + T) + cj);
            rcn = *(const float4*)(Cm + bbase + (ss + T) + cj);
        }

        float yreg[4];   // lane sub keeps y for timesteps sub*4..sub*4+3

#define CSTEP(ii) { \
        const float dt  = dpp_qp<(((ii) >> 2) * 0x55)>(dc[(ii) & 3]); \
        const float uu  = dpp_qp<(((ii) >> 2) * 0x55)>(uc[(ii) & 3]); \
        const float dtu = dt * uu; \
        const float4 bv = *(const float4*)(&LB[(ii) * LBSTR + cj]); \
        const float4 cv = *(const float4*)(&LC[(ii) * LBSTR + cj]); \
        x[0] = fmaf(exp2_hw(dt * A2[0]), x[0], dtu * bv.x); \
        x[1] = fmaf(exp2_hw(dt * A2[1]), x[1], dtu * bv.y); \
        x[2] = fmaf(exp2_hw(dt * A2[2]), x[2], dtu * bv.z); \
        x[3] = fmaf(exp2_hw(dt * A2[3]), x[3], dtu * bv.w); \
        float acc = x[0] * cv.x; \
        acc = fmaf(x[1], cv.y, acc); \
        acc = fmaf(x[2], cv.z, acc); \
        acc = fmaf(x[3], cv.w, acc); \
        acc = quad_sum(acc); \
        const float yv = fmaf(Dval, uu, acc); \
        if (sub == ((ii) >> 2)) yreg[(ii) & 3] = yv; \
    }
        CSTEP(0)  CSTEP(1)  CSTEP(2)  CSTEP(3)
        CSTEP(4)  CSTEP(5)  CSTEP(6)  CSTEP(7)
        CSTEP(8)  CSTEP(9)  CSTEP(10) CSTEP(11)
        CSTEP(12) CSTEP(13) CSTEP(14) CSTEP(15)
#undef CSTEP

        // quad writes 64B contiguous of this channel's y row
        *(float4*)(y + ubase + ss + sub * 4) =
            make_float4(yreg[0], yreg[1], yreg[2], yreg[3]);
    }
}

extern "C" void kernel_launch(void* const* d_in, const int* in_sizes, int n_in,
                              void* d_out, int out_size, void* d_ws, size_t ws_size,
                              hipStream_t stream)
{
    const float* u     = (const float*)d_in[0];
    const float* delta = (const float*)d_in[1];
    const float* Bm    = (const float*)d_in[2];
    const float* Cm    = (const float*)d_in[3];
    const float* A     = (const float*)d_in[4];
    const float* Dv    = (const float*)d_in[5];
    const float* dbias = (const float*)d_in[6];
    float* y = (float*)d_out;

    // workspace: sumdt [NCH*NCHAN] then S/x0 [NCH*NCHAN*NST]  (~13.4 MB total)
    float* sumdt = (float*)d_ws;
    float* S     = sumdt + (size_t)NCHAN * NCH;

    const dim3 grid(NCHAN / 64, NCH);
    ssm_phaseA<<<grid, 256, 0, stream>>>(u, delta, Bm, A, dbias, sumdt, S);
    ssm_phaseB<<<(NCHAN * NST) / 256, 256, 0, stream>>>(A, sumdt, S);
    ssm_phaseC<<<grid, 256, 0, stream>>>(u, delta, Bm, Cm, A, Dv, dbias, S, y);
}